// Round 3
// baseline (16003.206 us; speedup 1.0000x reference)
//
#include <hip/hip_runtime.h>
#include <hip/hip_bf16.h>

// ---------------- problem constants ----------------
#define TSEQ 2048
#define NB   4
#define DIM_ 2048
#define NHEAD 16
#define NKV  4
#define DH_  128
#define NTOK (NB * TSEQ)          // 8192
#define QKVN 3072                 // 2048 q + 512 k + 512 v

__device__ __forceinline__ unsigned short f2bfu(float f) {
  unsigned int u = __builtin_bit_cast(unsigned int, f);
  u += 0x7fffu + ((u >> 16) & 1u);        // round-to-nearest-even
  return (unsigned short)(u >> 16);
}
__device__ __forceinline__ float bfu2f(unsigned short h) {
  return __builtin_bit_cast(float, (unsigned int)h << 16);
}

__device__ __forceinline__ float ldf(const float* p, size_t i) { return p[i]; }
__device__ __forceinline__ float ldf(const unsigned short* p, size_t i) { return bfu2f(p[i]); }
__device__ __forceinline__ void stf(float* p, size_t i, float v) { p[i] = v; }
__device__ __forceinline__ void stf(unsigned short* p, size_t i, float v) { p[i] = f2bfu(v); }

// ---------------- pass 0: rope table sc[t][f] = (cos, sin) ----------------
__global__ void rope_table_kernel(const int* __restrict__ seq_start, float2* __restrict__ sc) {
  int i = blockIdx.x * blockDim.x + threadIdx.x;   // TSEQ*32 threads
  int t = i >> 5, f = i & 31;
  float pos = (float)(t + seq_start[0]);
  float inv = powf(10000.0f, -(float)f * (1.0f / 32.0f));  // 10000^(-f/32)
  float a = pos * inv;
  sc[i] = make_float2(cosf(a), sinf(a));
}

// ---------------- anchor GEMM: C[M][N] = A[M][K] * Bsel[N][K]^T ----------------
// B rows selected from up to 3 source matrices (wq/wk/wv concat) by global column:
// gc < c1 -> B0 row gc ; gc < c2 -> B1 row gc-c1 ; else B2 row gc-c2.
// 64x64 tile, BK=16, 256 threads, 4x4 micro-tile per thread. Plain VALU fp32.
template <typename AT, typename OT>
__global__ __launch_bounds__(256) void gemm_anchor(const AT* __restrict__ A,
                                                   const float* __restrict__ B0,
                                                   const float* __restrict__ B1,
                                                   const float* __restrict__ B2,
                                                   OT* __restrict__ C,
                                                   int M, int N, int K, int c1, int c2) {
  __shared__ float As[16][66];   // [k][m], pad to 66 to break bank patterns
  __shared__ float Bs[16][66];   // [k][n]
  const int tid = threadIdx.x, tx = tid & 15, ty = tid >> 4;
  const int row0 = blockIdx.y << 6, col0 = blockIdx.x << 6;
  float acc[4][4] = {};
  for (int kk = 0; kk < K; kk += 16) {
#pragma unroll
    for (int i = 0; i < 4; ++i) {
      const int idx = tid + (i << 8);            // 0..1023
      const int r = idx >> 4, c = idx & 15;      // r: row/col in tile, c: k offset
      As[c][r] = ldf(A, (size_t)(row0 + r) * K + kk + c);
      const int gc = col0 + r;
      const float* bp = (gc < c1) ? (B0 + (size_t)gc * K)
                                  : ((gc < c2) ? (B1 + (size_t)(gc - c1) * K)
                                               : (B2 + (size_t)(gc - c2) * K));
      Bs[c][r] = bp[kk + c];
    }
    __syncthreads();
#pragma unroll
    for (int k = 0; k < 16; ++k) {
      float ar[4], br[4];
#pragma unroll
      for (int i = 0; i < 4; ++i) ar[i] = As[k][(ty << 2) + i];
#pragma unroll
      for (int j = 0; j < 4; ++j) br[j] = Bs[k][(tx << 2) + j];
#pragma unroll
      for (int i = 0; i < 4; ++i)
#pragma unroll
        for (int j = 0; j < 4; ++j) acc[i][j] += ar[i] * br[j];
    }
    __syncthreads();
  }
#pragma unroll
  for (int i = 0; i < 4; ++i)
#pragma unroll
    for (int j = 0; j < 4; ++j)
      stf(C, (size_t)(row0 + (ty << 2) + i) * N + col0 + (tx << 2) + j, acc[i][j]);
}

// ---------------- pass 2: in-place RMSNorm + RoPE on q/k inside qkv ----------------
// one wave per (token, head 0..19): heads 0..15 -> q at col h*128, 16..19 -> k at 2048+(h-16)*128
__global__ __launch_bounds__(256) void norm_rope_kernel(const float2* __restrict__ sc,
                                                        unsigned short* __restrict__ qkv) {
  __shared__ float buf[4][128];
  const int wv = threadIdx.x >> 6, lane = threadIdx.x & 63;
  const int gid = blockIdx.x * 4 + wv;           // (tok, head) pair
  const int tok = gid / 20, hd = gid % 20;
  const int t = tok & (TSEQ - 1);
  unsigned short* row = qkv + (size_t)tok * QKVN + (hd < 16 ? hd * DH_ : 2048 + (hd - 16) * DH_);
  const unsigned int pp = *(const unsigned int*)(row + 2 * lane);
  float v0 = bfu2f((unsigned short)(pp & 0xffffu));
  float v1 = bfu2f((unsigned short)(pp >> 16));
  float ss = v0 * v0 + v1 * v1;
#pragma unroll
  for (int m = 1; m < 64; m <<= 1) ss += __shfl_xor(ss, m, 64);
  const float rn = rsqrtf(ss * (1.0f / 128.0f) + 1e-6f);
  v0 *= rn; v1 *= rn;
  if (lane < 32) {                               // rotary pair (x1,x2) = dims (2*lane, 2*lane+1)
    const float2 cs = sc[t * 32 + lane];
    buf[wv][lane]      = v0 * cs.x - v1 * cs.y;  // out dim lane
    buf[wv][lane + 32] = v0 * cs.y + v1 * cs.x;  // out dim lane+32
  } else {                                       // passthrough dims 64..127 (normalized)
    buf[wv][2 * lane]     = v0;
    buf[wv][2 * lane + 1] = v1;
  }
  const float o0 = buf[wv][2 * lane], o1 = buf[wv][2 * lane + 1];
  const unsigned int out = (unsigned int)f2bfu(o0) | ((unsigned int)f2bfu(o1) << 16);
  *(unsigned int*)(row + 2 * lane) = out;
}

// ---------------- pass 3: exact 2-pass causal attention, one block per (q-row, b, h) ----------------
__global__ __launch_bounds__(256) void attn_anchor(const unsigned short* __restrict__ qkv,
                                                   unsigned short* __restrict__ y) {
  __shared__ float qs[DH_];
  __shared__ float sbuf[TSEQ];
  __shared__ float red[256];
  __shared__ float obuf[2][DH_];
  const int t = blockIdx.x, bh = blockIdx.y;
  const int b = bh >> 4, h = bh & 15, kv = h >> 2;
  const int tid = threadIdx.x;
  if (tid < DH_) qs[tid] = bfu2f(qkv[(size_t)(b * TSEQ + t) * QKVN + h * DH_ + tid]);
  __syncthreads();
  const int nk = t + 1;                           // causal: keys 0..t
  // phase 1: scores
  float lmax = -3.0e38f;
  for (int j = tid; j < nk; j += 256) {
    const unsigned int* kp2 =
        (const unsigned int*)(qkv + (size_t)(b * TSEQ + j) * QKVN + 2048 + kv * DH_);
    float s = 0.f;
#pragma unroll
    for (int d2 = 0; d2 < 64; ++d2) {
      const unsigned int pp = kp2[d2];
      s += qs[2 * d2]     * bfu2f((unsigned short)(pp & 0xffffu));
      s += qs[2 * d2 + 1] * bfu2f((unsigned short)(pp >> 16));
    }
    s *= 0.12f;
    sbuf[j] = s;
    lmax = fmaxf(lmax, s);
  }
  red[tid] = lmax;
  __syncthreads();
  for (int off = 128; off; off >>= 1) {
    if (tid < off) red[tid] = fmaxf(red[tid], red[tid + off]);
    __syncthreads();
  }
  const float m = red[0];
  // phase 2: exp + sum
  float lsum = 0.f;
  for (int j = tid; j < nk; j += 256) {
    const float p = __expf(sbuf[j] - m);
    sbuf[j] = p;
    lsum += p;
  }
  __syncthreads();                                // all reads of red[0] done before overwrite
  red[tid] = lsum;
  __syncthreads();
  for (int off = 128; off; off >>= 1) {
    if (tid < off) red[tid] += red[tid + off];
    __syncthreads();
  }
  const float l = red[0];
  // phase 3: o[d] = sum_j p[j] * V[j][d]   (two t-slices, combined via LDS)
  const int d = tid & (DH_ - 1), half = tid >> 7;
  float acc = 0.f;
  for (int j = half; j < nk; j += 2)
    acc += sbuf[j] * bfu2f(qkv[(size_t)(b * TSEQ + j) * QKVN + 2560 + kv * DH_ + d]);
  obuf[half][d] = acc;
  __syncthreads();
  if (tid < DH_)
    y[(size_t)(b * TSEQ + t) * (NHEAD * DH_) + h * DH_ + tid] =
        f2bfu((obuf[0][tid] + obuf[1][tid]) / l);
}

// ---------------- launcher ----------------
extern "C" void kernel_launch(void* const* d_in, const int* in_sizes, int n_in,
                              void* d_out, int out_size, void* d_ws, size_t ws_size,
                              hipStream_t stream) {
  const float* x   = (const float*)d_in[0];
  const int* seq0  = (const int*)d_in[1];
  // d_in[2] = attn_mask (tril causal) — handled analytically
  const float* wq  = (const float*)d_in[3];
  const float* wk  = (const float*)d_in[4];
  const float* wvp = (const float*)d_in[5];
  const float* wo  = (const float*)d_in[6];
  float* out = (float*)d_out;
  char* ws = (char*)d_ws;

  const size_t qkv_e = (size_t)NTOK * QKVN;               // 25,165,824 bf16 = 50.3 MB
  const size_t y_e   = (size_t)NTOK * (NHEAD * DH_);      // 16,777,216 bf16 = 33.6 MB

  unsigned short* qkvb = (unsigned short*)ws;
  unsigned short* yb   = qkvb + qkv_e;
  float2* sc           = (float2*)(yb + y_e);
  const size_t need = (size_t)((char*)(sc + TSEQ * 32) - ws);   // ~84.4 MiB
  if (ws_size < need) {
    hipMemsetAsync(d_out, 0x7f, 256, stream);  // sentinel: absmax ~3.4e38 => ws too small
    return;
  }

  rope_table_kernel<<<(TSEQ * 32) / 256, 256, 0, stream>>>(seq0, sc);

  // qkv = x @ [wq;wk;wv]^T   (fp32 in, bf16 out)
  gemm_anchor<float, unsigned short><<<dim3(QKVN / 64, NTOK / 64), 256, 0, stream>>>(
      x, wq, wk, wvp, qkvb, NTOK, QKVN, DIM_, 2048, 2560);

  // in-place rmsnorm + rope on q,k heads
  norm_rope_kernel<<<NTOK * 20 / 4, 256, 0, stream>>>(sc, qkvb);

  // causal attention
  attn_anchor<<<dim3(TSEQ, NB * NHEAD), 256, 0, stream>>>(qkvb, yb);

  // out = y @ wo^T   (bf16 A, fp32 B, fp32 out)
  gemm_anchor<unsigned short, float><<<dim3(DIM_ / 64, NTOK / 64), 256, 0, stream>>>(
      yb, wo, wo, wo, out, NTOK, DIM_, DIM_, DIM_, DIM_);
}

// Round 4
// 3703.867 us; speedup vs baseline: 4.3207x; 4.3207x over previous
//
#include <hip/hip_runtime.h>
#include <hip/hip_bf16.h>

// ---------------- problem constants ----------------
#define TSEQ 2048
#define NB   4
#define DIM_ 2048
#define NHEAD 16
#define NKV  4
#define DH_  128
#define NTOK (NB * TSEQ)          // 8192
#define QKVN 3072                 // 2048 q + 512 k + 512 v

typedef short short8 __attribute__((ext_vector_type(8)));
typedef float f32x4  __attribute__((ext_vector_type(4)));

__device__ __forceinline__ unsigned short f2bfu(float f) {
  unsigned int u = __builtin_bit_cast(unsigned int, f);
  u += 0x7fffu + ((u >> 16) & 1u);        // round-to-nearest-even
  return (unsigned short)(u >> 16);
}
__device__ __forceinline__ float bfu2f(unsigned short h) {
  return __builtin_bit_cast(float, (unsigned int)h << 16);
}

__device__ __forceinline__ float ldf(const float* p, size_t i) { return p[i]; }
__device__ __forceinline__ float ldf(const unsigned short* p, size_t i) { return bfu2f(p[i]); }
__device__ __forceinline__ void stf(float* p, size_t i, float v) { p[i] = v; }
__device__ __forceinline__ void stf(unsigned short* p, size_t i, float v) { p[i] = f2bfu(v); }

// ---------------- pass 0: rope table sc[t][f] = (cos, sin) ----------------
__global__ void rope_table_kernel(const int* __restrict__ seq_start, float2* __restrict__ sc) {
  int i = blockIdx.x * blockDim.x + threadIdx.x;   // TSEQ*32 threads
  int t = i >> 5, f = i & 31;
  float pos = (float)(t + seq_start[0]);
  float inv = powf(10000.0f, -(float)f * (1.0f / 32.0f));  // 10000^(-f/32)
  float a = pos * inv;
  sc[i] = make_float2(cosf(a), sinf(a));
}

// ---------------- anchor GEMM: C[M][N] = A[M][K] * Bsel[N][K]^T ----------------
template <typename AT, typename OT>
__global__ __launch_bounds__(256) void gemm_anchor(const AT* __restrict__ A,
                                                   const float* __restrict__ B0,
                                                   const float* __restrict__ B1,
                                                   const float* __restrict__ B2,
                                                   OT* __restrict__ C,
                                                   int M, int N, int K, int c1, int c2) {
  __shared__ float As[16][66];   // [k][m]
  __shared__ float Bs[16][66];   // [k][n]
  const int tid = threadIdx.x, tx = tid & 15, ty = tid >> 4;
  const int row0 = blockIdx.y << 6, col0 = blockIdx.x << 6;
  float acc[4][4] = {};
  for (int kk = 0; kk < K; kk += 16) {
#pragma unroll
    for (int i = 0; i < 4; ++i) {
      const int idx = tid + (i << 8);            // 0..1023
      const int r = idx >> 4, c = idx & 15;
      As[c][r] = ldf(A, (size_t)(row0 + r) * K + kk + c);
      const int gc = col0 + r;
      const float* bp = (gc < c1) ? (B0 + (size_t)gc * K)
                                  : ((gc < c2) ? (B1 + (size_t)(gc - c1) * K)
                                               : (B2 + (size_t)(gc - c2) * K));
      Bs[c][r] = bp[kk + c];
    }
    __syncthreads();
#pragma unroll
    for (int k = 0; k < 16; ++k) {
      float ar[4], br[4];
#pragma unroll
      for (int i = 0; i < 4; ++i) ar[i] = As[k][(ty << 2) + i];
#pragma unroll
      for (int j = 0; j < 4; ++j) br[j] = Bs[k][(tx << 2) + j];
#pragma unroll
      for (int i = 0; i < 4; ++i)
#pragma unroll
        for (int j = 0; j < 4; ++j) acc[i][j] += ar[i] * br[j];
    }
    __syncthreads();
  }
#pragma unroll
  for (int i = 0; i < 4; ++i)
#pragma unroll
    for (int j = 0; j < 4; ++j)
      stf(C, (size_t)(row0 + (ty << 2) + i) * N + col0 + (tx << 2) + j, acc[i][j]);
}

// ---------------- pass 2: in-place RMSNorm + RoPE on q/k inside qkv ----------------
__global__ __launch_bounds__(256) void norm_rope_kernel(const float2* __restrict__ sc,
                                                        unsigned short* __restrict__ qkv) {
  __shared__ float buf[4][128];
  const int wv = threadIdx.x >> 6, lane = threadIdx.x & 63;
  const int gid = blockIdx.x * 4 + wv;           // (tok, head) pair
  const int tok = gid / 20, hd = gid % 20;
  const int t = tok & (TSEQ - 1);
  unsigned short* row = qkv + (size_t)tok * QKVN + (hd < 16 ? hd * DH_ : 2048 + (hd - 16) * DH_);
  const unsigned int pp = *(const unsigned int*)(row + 2 * lane);
  float v0 = bfu2f((unsigned short)(pp & 0xffffu));
  float v1 = bfu2f((unsigned short)(pp >> 16));
  float ss = v0 * v0 + v1 * v1;
#pragma unroll
  for (int m = 1; m < 64; m <<= 1) ss += __shfl_xor(ss, m, 64);
  const float rn = rsqrtf(ss * (1.0f / 128.0f) + 1e-6f);
  v0 *= rn; v1 *= rn;
  if (lane < 32) {                               // rotary pair (x1,x2) = dims (2*lane, 2*lane+1)
    const float2 cs = sc[t * 32 + lane];
    buf[wv][lane]      = v0 * cs.x - v1 * cs.y;  // out dim lane
    buf[wv][lane + 32] = v0 * cs.y + v1 * cs.x;  // out dim lane+32
  } else {                                       // passthrough dims 64..127 (normalized)
    buf[wv][2 * lane]     = v0;
    buf[wv][2 * lane + 1] = v1;
  }
  const float o0 = buf[wv][2 * lane], o1 = buf[wv][2 * lane + 1];
  const unsigned int out = (unsigned int)f2bfu(o0) | ((unsigned int)f2bfu(o1) << 16);
  *(unsigned int*)(row + 2 * lane) = out;
}

// ---------------- pass 3: MFMA causal flash attention (natural qkv layout) ----------------
// grid (TSEQ/64, NB*NHEAD); 4 waves x 16 q-rows; K-tile = 32
__global__ __launch_bounds__(256) void attn_kernel(const unsigned short* __restrict__ qkv,
                                                   unsigned short* __restrict__ yb) {
  __shared__ __align__(16) unsigned short Ks[32][136];   // [key][d], padded
  __shared__ __align__(16) unsigned short Vs[128][40];   // [d][key], padded
  __shared__ __align__(16) unsigned short Ps[4][16][40]; // per-wave P bounce
  const int qt = blockIdx.x, bh = blockIdx.y;
  const int b = bh >> 4, h = bh & 15, kv = h >> 2;       // h = kv*GROUPS + g
  const int tid = threadIdx.x, lane = tid & 63, wv = tid >> 6;
  const int q0 = qt << 6;
  const int lo = lane & 15, hi = lane >> 4;
  const unsigned short* base = qkv + (size_t)b * TSEQ * QKVN;
  short8 qf[4];
#pragma unroll
  for (int ch = 0; ch < 4; ++ch)
    qf[ch] = *(const short8*)(base + (size_t)(q0 + (wv << 4) + lo) * QKVN + h * DH_ +
                              ch * 32 + hi * 8);
  float m_r[4] = {-1e30f, -1e30f, -1e30f, -1e30f};
  float l_r[4] = {0.f, 0.f, 0.f, 0.f};
  f32x4 oacc[8] = {};
  const int rbase = q0 + (wv << 4) + (hi << 2);
  for (int t0 = 0; t0 <= q0 + 63; t0 += 32) {
    __syncthreads();
#pragma unroll
    for (int it = 0; it < 2; ++it) {                 // stage K tile 32x128 (row stride QKVN)
      int idx = tid + (it << 8);
      int r = idx >> 4, c8 = (idx & 15) << 3;
      *(short8*)&Ks[r][c8] =
          *(const short8*)(base + (size_t)(t0 + r) * QKVN + 2048 + kv * DH_ + c8);
    }
#pragma unroll
    for (int it = 0; it < 2; ++it) {                 // stage V tile transposed -> Vs[d][key]
      int idx = tid + (it << 8);
      int tl = idx >> 4, c8 = (idx & 15) << 3;
      short8 vrow = *(const short8*)(base + (size_t)(t0 + tl) * QKVN + 2560 + kv * DH_ + c8);
#pragma unroll
      for (int j = 0; j < 8; ++j) Vs[c8 + j][tl] = (unsigned short)vrow[j];
    }
    __syncthreads();
    f32x4 sacc[2] = {};
#pragma unroll
    for (int c = 0; c < 2; ++c)
#pragma unroll
      for (int ch = 0; ch < 4; ++ch) {
        short8 kf = *(const short8*)&Ks[(c << 4) + lo][ch * 32 + hi * 8];
        sacc[c] = __builtin_amdgcn_mfma_f32_16x16x32_bf16(qf[ch], kf, sacc[c], 0, 0, 0);
      }
    float p0[4], p1[4], tm[4];
#pragma unroll
    for (int r = 0; r < 4; ++r) {
      float s0 = sacc[0][r] * 0.12f, s1 = sacc[1][r] * 0.12f;
      const int rg = rbase + r;
      if (t0 + lo > rg)      s0 = -1e30f;            // causal mask
      if (t0 + 16 + lo > rg) s1 = -1e30f;
      p0[r] = s0; p1[r] = s1;
      tm[r] = fmaxf(s0, s1);
    }
#pragma unroll
    for (int mm = 1; mm < 16; mm <<= 1)
#pragma unroll
      for (int r = 0; r < 4; ++r) tm[r] = fmaxf(tm[r], __shfl_xor(tm[r], mm, 64));
    float fac[4], rs[4];
#pragma unroll
    for (int r = 0; r < 4; ++r) {
      float mn = fmaxf(m_r[r], tm[r]);
      fac[r] = __expf(m_r[r] - mn);
      m_r[r] = mn;
      p0[r] = __expf(p0[r] - mn);
      p1[r] = __expf(p1[r] - mn);
      rs[r] = p0[r] + p1[r];
    }
#pragma unroll
    for (int mm = 1; mm < 16; mm <<= 1)
#pragma unroll
      for (int r = 0; r < 4; ++r) rs[r] += __shfl_xor(rs[r], mm, 64);
#pragma unroll
    for (int r = 0; r < 4; ++r) l_r[r] = l_r[r] * fac[r] + rs[r];
#pragma unroll
    for (int dt = 0; dt < 8; ++dt)
#pragma unroll
      for (int r = 0; r < 4; ++r) oacc[dt][r] *= fac[r];
#pragma unroll
    for (int r = 0; r < 4; ++r) {                    // P (D-layout) -> LDS
      Ps[wv][(hi << 2) + r][lo]      = f2bfu(p0[r]);
      Ps[wv][(hi << 2) + r][16 + lo] = f2bfu(p1[r]);
    }
    short8 pf = *(const short8*)&Ps[wv][lo][hi * 8]; // P back in A-frag layout
#pragma unroll
    for (int dt = 0; dt < 8; ++dt) {
      short8 vf = *(const short8*)&Vs[(dt << 4) + lo][hi * 8];
      oacc[dt] = __builtin_amdgcn_mfma_f32_16x16x32_bf16(pf, vf, oacc[dt], 0, 0, 0);
    }
  }
#pragma unroll
  for (int r = 0; r < 4; ++r) {
    const int rg = rbase + r;
    const float inv = 1.0f / l_r[r];
#pragma unroll
    for (int dt = 0; dt < 8; ++dt)
      yb[(size_t)(b * TSEQ + rg) * (NHEAD * DH_) + h * DH_ + (dt << 4) + lo] =
          f2bfu(oacc[dt][r] * inv);
  }
}

// ---------------- launcher ----------------
extern "C" void kernel_launch(void* const* d_in, const int* in_sizes, int n_in,
                              void* d_out, int out_size, void* d_ws, size_t ws_size,
                              hipStream_t stream) {
  const float* x   = (const float*)d_in[0];
  const int* seq0  = (const int*)d_in[1];
  // d_in[2] = attn_mask (tril causal) — handled analytically
  const float* wq  = (const float*)d_in[3];
  const float* wk  = (const float*)d_in[4];
  const float* wvp = (const float*)d_in[5];
  const float* wo  = (const float*)d_in[6];
  float* out = (float*)d_out;
  char* ws = (char*)d_ws;

  const size_t qkv_e = (size_t)NTOK * QKVN;               // 50.3 MB bf16
  const size_t y_e   = (size_t)NTOK * (NHEAD * DH_);      // 33.6 MB bf16

  unsigned short* qkvb = (unsigned short*)ws;
  unsigned short* yb   = qkvb + qkv_e;
  float2* sc           = (float2*)(yb + y_e);
  const size_t need = (size_t)((char*)(sc + TSEQ * 32) - ws);   // ~84.4 MiB
  if (ws_size < need) {
    hipMemsetAsync(d_out, 0x7f, 256, stream);  // sentinel: absmax ~3.4e38 => ws too small
    return;
  }

  rope_table_kernel<<<(TSEQ * 32) / 256, 256, 0, stream>>>(seq0, sc);

  // qkv = x @ [wq;wk;wv]^T   (fp32 in, bf16 out)
  gemm_anchor<float, unsigned short><<<dim3(QKVN / 64, NTOK / 64), 256, 0, stream>>>(
      x, wq, wk, wvp, qkvb, NTOK, QKVN, DIM_, 2048, 2560);

  // in-place rmsnorm + rope on q,k heads
  norm_rope_kernel<<<NTOK * 20 / 4, 256, 0, stream>>>(sc, qkvb);

  // MFMA causal flash attention
  attn_kernel<<<dim3(TSEQ / 64, NB * NHEAD), 256, 0, stream>>>(qkvb, yb);

  // out = y @ wo^T   (bf16 A, fp32 B, fp32 out)
  gemm_anchor<unsigned short, float><<<dim3(DIM_ / 64, NTOK / 64), 256, 0, stream>>>(
      yb, wo, wo, wo, out, NTOK, DIM_, DIM_, DIM_, DIM_);
}

// Round 5
// 1213.139 us; speedup vs baseline: 13.1916x; 3.0531x over previous
//
#include <hip/hip_runtime.h>
#include <hip/hip_bf16.h>

// ---------------- problem constants ----------------
#define TSEQ 2048
#define NB   4
#define DIM_ 2048
#define NHEAD 16
#define NKV  4
#define DH_  128
#define NTOK (NB * TSEQ)          // 8192
#define QKVN 3072                 // 2048 q + 512 k + 512 v

typedef short short8 __attribute__((ext_vector_type(8)));
typedef float f32x4  __attribute__((ext_vector_type(4)));

__device__ __forceinline__ unsigned short f2bfu(float f) {
  unsigned int u = __builtin_bit_cast(unsigned int, f);
  u += 0x7fffu + ((u >> 16) & 1u);        // round-to-nearest-even
  return (unsigned short)(u >> 16);
}
__device__ __forceinline__ float bfu2f(unsigned short h) {
  return __builtin_bit_cast(float, (unsigned int)h << 16);
}

#define GLOAD_LDS16(gp, lp)                                                           \
  __builtin_amdgcn_global_load_lds((const __attribute__((address_space(1))) void*)(gp), \
                                   (__attribute__((address_space(3))) void*)(lp), 16, 0, 0)

// ---------------- pass 0: fp32 -> bf16 ----------------
__global__ void cvt_kernel(const float* __restrict__ s, unsigned short* __restrict__ d, int n4) {
  int i = blockIdx.x * blockDim.x + threadIdx.x;
  int st = gridDim.x * blockDim.x;
  for (; i < n4; i += st) {
    float4 v = ((const float4*)s)[i];
    ushort4 o;
    o.x = f2bfu(v.x); o.y = f2bfu(v.y); o.z = f2bfu(v.z); o.w = f2bfu(v.w);
    ((ushort4*)d)[i] = o;
  }
}

// ---------------- pass 0b: rope table sc[t][f] = (cos, sin) ----------------
__global__ void rope_table_kernel(const int* __restrict__ seq_start, float2* __restrict__ sc) {
  int i = blockIdx.x * blockDim.x + threadIdx.x;   // TSEQ*32 threads
  int t = i >> 5, f = i & 31;
  float pos = (float)(t + seq_start[0]);
  float inv = powf(10000.0f, -(float)f * (1.0f / 32.0f));  // 10000^(-f/32)
  float a = pos * inv;
  sc[i] = make_float2(cosf(a), sinf(a));
}

// ---------------- MFMA GEMM: C[M][N] = A[M][K] * B[N][K]^T (bf16 in, m97 structure) ----------------
__device__ __forceinline__ void store_out(float* C, size_t i, float v) { C[i] = v; }
__device__ __forceinline__ void store_out(unsigned short* C, size_t i, float v) { C[i] = f2bfu(v); }

template <typename OutT>
__global__ __launch_bounds__(256) void gemm_bt(const unsigned short* __restrict__ A,
                                               const unsigned short* __restrict__ Bm,
                                               OutT* __restrict__ C, int M, int N, int K) {
  __shared__ __align__(16) unsigned short As[128 * 32];
  __shared__ __align__(16) unsigned short Bs[128 * 32];
  const int tid = threadIdx.x, lane = tid & 63, wv = tid >> 6;
  const int wm = wv >> 1, wn = wv & 1;
  const int row0 = blockIdx.y << 7, col0 = blockIdx.x << 7;
  const int lo = lane & 15, krd = (lane >> 4) << 3;
  f32x4 acc[4][4] = {};
  for (int kk = 0; kk < K; kk += 32) {
    __syncthreads();
#pragma unroll
    for (int half = 0; half < 2; ++half) {
      const int seg  = wv + (half << 2);             // wave-uniform LDS segment 0..7
      const int boff = seg * 1024 + lane * 16;       // byte offset in the 8 KB tile
      const int r    = boff >> 6;                    // row (64B per row of 32 bf16)
      const int ce   = (boff & 63) >> 1;             // element col
      GLOAD_LDS16(A  + (size_t)(row0 + r) * K + kk + ce, (char*)As + seg * 1024);
      GLOAD_LDS16(Bm + (size_t)(col0 + r) * K + kk + ce, (char*)Bs + seg * 1024);
    }
    asm volatile("s_waitcnt vmcnt(0)" ::: "memory");
    __syncthreads();
    short8 af[4], bf[4];
#pragma unroll
    for (int i = 0; i < 4; ++i)
      af[i] = *(const short8*)&As[((wm << 6) + (i << 4) + lo) * 32 + krd];
#pragma unroll
    for (int j = 0; j < 4; ++j)
      bf[j] = *(const short8*)&Bs[((wn << 6) + (j << 4) + lo) * 32 + krd];
#pragma unroll
    for (int i = 0; i < 4; ++i)
#pragma unroll
      for (int j = 0; j < 4; ++j)
        acc[i][j] = __builtin_amdgcn_mfma_f32_16x16x32_bf16(af[i], bf[j], acc[i][j], 0, 0, 0);
  }
#pragma unroll
  for (int i = 0; i < 4; ++i)
#pragma unroll
    for (int j = 0; j < 4; ++j) {
      const int r = row0 + (wm << 6) + (i << 4) + ((lane >> 4) << 2);
      const int c = col0 + (wn << 6) + (j << 4) + lo;
#pragma unroll
      for (int rr = 0; rr < 4; ++rr)
        store_out(C, (size_t)(r + rr) * N + c, acc[i][j][rr]);
    }
}

// ---------------- pass 2: in-place RMSNorm + RoPE on q/k inside qkv ----------------
__global__ __launch_bounds__(256) void norm_rope_kernel(const float2* __restrict__ sc,
                                                        unsigned short* __restrict__ qkv) {
  __shared__ float buf[4][128];
  const int wv = threadIdx.x >> 6, lane = threadIdx.x & 63;
  const int gid = blockIdx.x * 4 + wv;           // (tok, head) pair
  const int tok = gid / 20, hd = gid % 20;
  const int t = tok & (TSEQ - 1);
  unsigned short* row = qkv + (size_t)tok * QKVN + (hd < 16 ? hd * DH_ : 2048 + (hd - 16) * DH_);
  const unsigned int pp = *(const unsigned int*)(row + 2 * lane);
  float v0 = bfu2f((unsigned short)(pp & 0xffffu));
  float v1 = bfu2f((unsigned short)(pp >> 16));
  float ss = v0 * v0 + v1 * v1;
#pragma unroll
  for (int m = 1; m < 64; m <<= 1) ss += __shfl_xor(ss, m, 64);
  const float rn = rsqrtf(ss * (1.0f / 128.0f) + 1e-6f);
  v0 *= rn; v1 *= rn;
  if (lane < 32) {                               // rotary pair (x1,x2) = dims (2*lane, 2*lane+1)
    const float2 cs = sc[t * 32 + lane];
    buf[wv][lane]      = v0 * cs.x - v1 * cs.y;  // out dim lane
    buf[wv][lane + 32] = v0 * cs.y + v1 * cs.x;  // out dim lane+32
  } else {                                       // passthrough dims 64..127 (normalized)
    buf[wv][2 * lane]     = v0;
    buf[wv][2 * lane + 1] = v1;
  }
  const float o0 = buf[wv][2 * lane], o1 = buf[wv][2 * lane + 1];
  const unsigned int out = (unsigned int)f2bfu(o0) | ((unsigned int)f2bfu(o1) << 16);
  *(unsigned int*)(row + 2 * lane) = out;
}

// ---------------- pass 3: MFMA causal flash attention (natural qkv layout) ----------------
// grid (TSEQ/64, NB*NHEAD); 4 waves x 16 q-rows; K-tile = 32
__global__ __launch_bounds__(256) void attn_kernel(const unsigned short* __restrict__ qkv,
                                                   unsigned short* __restrict__ yb) {
  __shared__ __align__(16) unsigned short Ks[32][136];   // [key][d], padded
  __shared__ __align__(16) unsigned short Vs[128][40];   // [d][key], padded
  __shared__ __align__(16) unsigned short Ps[4][16][40]; // per-wave P bounce
  const int qt = blockIdx.x, bh = blockIdx.y;
  const int b = bh >> 4, h = bh & 15, kv = h >> 2;       // h = kv*GROUPS + g
  const int tid = threadIdx.x, lane = tid & 63, wv = tid >> 6;
  const int q0 = qt << 6;
  const int lo = lane & 15, hi = lane >> 4;
  const unsigned short* base = qkv + (size_t)b * TSEQ * QKVN;
  short8 qf[4];
#pragma unroll
  for (int ch = 0; ch < 4; ++ch)
    qf[ch] = *(const short8*)(base + (size_t)(q0 + (wv << 4) + lo) * QKVN + h * DH_ +
                              ch * 32 + hi * 8);
  float m_r[4] = {-1e30f, -1e30f, -1e30f, -1e30f};
  float l_r[4] = {0.f, 0.f, 0.f, 0.f};
  f32x4 oacc[8] = {};
  const int rbase = q0 + (wv << 4) + (hi << 2);
  for (int t0 = 0; t0 <= q0 + 63; t0 += 32) {
    __syncthreads();
#pragma unroll
    for (int it = 0; it < 2; ++it) {                 // stage K tile 32x128 (row stride QKVN)
      int idx = tid + (it << 8);
      int r = idx >> 4, c8 = (idx & 15) << 3;
      *(short8*)&Ks[r][c8] =
          *(const short8*)(base + (size_t)(t0 + r) * QKVN + 2048 + kv * DH_ + c8);
    }
#pragma unroll
    for (int it = 0; it < 2; ++it) {                 // stage V tile transposed -> Vs[d][key]
      int idx = tid + (it << 8);
      int tl = idx >> 4, c8 = (idx & 15) << 3;
      short8 vrow = *(const short8*)(base + (size_t)(t0 + tl) * QKVN + 2560 + kv * DH_ + c8);
#pragma unroll
      for (int j = 0; j < 8; ++j) Vs[c8 + j][tl] = (unsigned short)vrow[j];
    }
    __syncthreads();
    f32x4 sacc[2] = {};
#pragma unroll
    for (int c = 0; c < 2; ++c)
#pragma unroll
      for (int ch = 0; ch < 4; ++ch) {
        short8 kf = *(const short8*)&Ks[(c << 4) + lo][ch * 32 + hi * 8];
        sacc[c] = __builtin_amdgcn_mfma_f32_16x16x32_bf16(qf[ch], kf, sacc[c], 0, 0, 0);
      }
    float p0[4], p1[4], tm[4];
#pragma unroll
    for (int r = 0; r < 4; ++r) {
      float s0 = sacc[0][r] * 0.12f, s1 = sacc[1][r] * 0.12f;
      const int rg = rbase + r;
      if (t0 + lo > rg)      s0 = -1e30f;            // causal mask
      if (t0 + 16 + lo > rg) s1 = -1e30f;
      p0[r] = s0; p1[r] = s1;
      tm[r] = fmaxf(s0, s1);
    }
#pragma unroll
    for (int mm = 1; mm < 16; mm <<= 1)
#pragma unroll
      for (int r = 0; r < 4; ++r) tm[r] = fmaxf(tm[r], __shfl_xor(tm[r], mm, 64));
    float fac[4], rs[4];
#pragma unroll
    for (int r = 0; r < 4; ++r) {
      float mn = fmaxf(m_r[r], tm[r]);
      fac[r] = __expf(m_r[r] - mn);
      m_r[r] = mn;
      p0[r] = __expf(p0[r] - mn);
      p1[r] = __expf(p1[r] - mn);
      rs[r] = p0[r] + p1[r];
    }
#pragma unroll
    for (int mm = 1; mm < 16; mm <<= 1)
#pragma unroll
      for (int r = 0; r < 4; ++r) rs[r] += __shfl_xor(rs[r], mm, 64);
#pragma unroll
    for (int r = 0; r < 4; ++r) l_r[r] = l_r[r] * fac[r] + rs[r];
#pragma unroll
    for (int dt = 0; dt < 8; ++dt)
#pragma unroll
      for (int r = 0; r < 4; ++r) oacc[dt][r] *= fac[r];
#pragma unroll
    for (int r = 0; r < 4; ++r) {                    // P (D-layout) -> LDS
      Ps[wv][(hi << 2) + r][lo]      = f2bfu(p0[r]);
      Ps[wv][(hi << 2) + r][16 + lo] = f2bfu(p1[r]);
    }
    short8 pf = *(const short8*)&Ps[wv][lo][hi * 8]; // P back in A-frag layout
#pragma unroll
    for (int dt = 0; dt < 8; ++dt) {
      short8 vf = *(const short8*)&Vs[(dt << 4) + lo][hi * 8];
      oacc[dt] = __builtin_amdgcn_mfma_f32_16x16x32_bf16(pf, vf, oacc[dt], 0, 0, 0);
    }
  }
#pragma unroll
  for (int r = 0; r < 4; ++r) {
    const int rg = rbase + r;
    const float inv = 1.0f / l_r[r];
#pragma unroll
    for (int dt = 0; dt < 8; ++dt)
      yb[(size_t)(b * TSEQ + rg) * (NHEAD * DH_) + h * DH_ + (dt << 4) + lo] =
          f2bfu(oacc[dt][r] * inv);
  }
}

// ---------------- launcher ----------------
extern "C" void kernel_launch(void* const* d_in, const int* in_sizes, int n_in,
                              void* d_out, int out_size, void* d_ws, size_t ws_size,
                              hipStream_t stream) {
  const float* x   = (const float*)d_in[0];
  const int* seq0  = (const int*)d_in[1];
  // d_in[2] = attn_mask (tril causal) — handled analytically
  const float* wq  = (const float*)d_in[3];
  const float* wk  = (const float*)d_in[4];
  const float* wvp = (const float*)d_in[5];
  const float* wo  = (const float*)d_in[6];
  float* out = (float*)d_out;
  char* ws = (char*)d_ws;

  const size_t xb_e   = (size_t)NTOK * DIM_;              // 16,777,216
  const size_t wqkv_e = (size_t)QKVN * DIM_;              //  6,291,456
  const size_t wo_e   = (size_t)DIM_ * DIM_;              //  4,194,304
  const size_t qkv_e  = (size_t)NTOK * QKVN;              // 25,165,824

  unsigned short* xb    = (unsigned short*)ws;
  unsigned short* wqkvb = xb + xb_e;
  unsigned short* wob   = wqkvb + wqkv_e;
  unsigned short* qkvb  = wob + wo_e;
  float2* sc            = (float2*)(qkvb + qkv_e);
  unsigned short* yb    = xb;                             // xb dead after GEMM1 — reuse
  const size_t need = (size_t)((char*)(sc + TSEQ * 32) - ws);   // 105,381,888 B (= round-1 size, known to fit)
  if (ws_size < need) {
    hipMemsetAsync(d_out, 0x7f, 256, stream);  // sentinel: absmax ~3.4e38 => ws too small
    return;
  }

  cvt_kernel<<<2048, 256, 0, stream>>>(x, xb, (int)(xb_e / 4));
  cvt_kernel<<<1024, 256, 0, stream>>>(wq, wqkvb, (int)(wo_e / 4));
  cvt_kernel<<<512, 256, 0, stream>>>(wk, wqkvb + (size_t)2048 * DIM_, (int)((size_t)512 * DIM_ / 4));
  cvt_kernel<<<512, 256, 0, stream>>>(wvp, wqkvb + (size_t)2560 * DIM_, (int)((size_t)512 * DIM_ / 4));
  cvt_kernel<<<1024, 256, 0, stream>>>(wo, wob, (int)(wo_e / 4));
  rope_table_kernel<<<(TSEQ * 32) / 256, 256, 0, stream>>>(seq0, sc);

  // qkv = x @ [wq;wk;wv]^T  -> natural layout [tok][3072] (bf16)
  gemm_bt<unsigned short><<<dim3(QKVN / 128, NTOK / 128), 256, 0, stream>>>(
      xb, wqkvb, qkvb, NTOK, QKVN, DIM_);

  // in-place rmsnorm + rope on q,k heads
  norm_rope_kernel<<<NTOK * 20 / 4, 256, 0, stream>>>(sc, qkvb);

  // MFMA causal flash attention
  attn_kernel<<<dim3(TSEQ / 64, NB * NHEAD), 256, 0, stream>>>(qkvb, yb);

  // out = y @ wo^T   (bf16 in, fp32 out)
  gemm_bt<float><<<dim3(DIM_ / 128, NTOK / 128), 256, 0, stream>>>(
      yb, wob, out, NTOK, DIM_, DIM_);
}

// Round 6
// 727.627 us; speedup vs baseline: 21.9937x; 1.6673x over previous
//
#include <hip/hip_runtime.h>
#include <hip/hip_bf16.h>

// ---------------- problem constants ----------------
#define TSEQ 2048
#define NB   4
#define DIM_ 2048
#define NHEAD 16
#define NKV  4
#define DH_  128
#define NTOK (NB * TSEQ)          // 8192
#define QKVN 3072                 // 2048 q + 512 k + 512 v

typedef short short8 __attribute__((ext_vector_type(8)));
typedef float f32x4  __attribute__((ext_vector_type(4)));

__device__ __forceinline__ unsigned short f2bfu(float f) {
  unsigned int u = __builtin_bit_cast(unsigned int, f);
  u += 0x7fffu + ((u >> 16) & 1u);        // round-to-nearest-even
  return (unsigned short)(u >> 16);
}
__device__ __forceinline__ float bfu2f(unsigned short h) {
  return __builtin_bit_cast(float, (unsigned int)h << 16);
}

#define GLOAD_LDS16(gp, lp)                                                           \
  __builtin_amdgcn_global_load_lds((const __attribute__((address_space(1))) void*)(gp), \
                                   (__attribute__((address_space(3))) void*)(lp), 16, 0, 0)

// ---------------- pass 0: fp32 -> bf16 ----------------
__global__ void cvt_kernel(const float* __restrict__ s, unsigned short* __restrict__ d, int n4) {
  int i = blockIdx.x * blockDim.x + threadIdx.x;
  int st = gridDim.x * blockDim.x;
  for (; i < n4; i += st) {
    float4 v = ((const float4*)s)[i];
    ushort4 o;
    o.x = f2bfu(v.x); o.y = f2bfu(v.y); o.z = f2bfu(v.z); o.w = f2bfu(v.w);
    ((ushort4*)d)[i] = o;
  }
}

// ---------------- pass 0b: rope table sc[t][f] = (cos, sin) ----------------
__global__ void rope_table_kernel(const int* __restrict__ seq_start, float2* __restrict__ sc) {
  int i = blockIdx.x * blockDim.x + threadIdx.x;   // TSEQ*32 threads
  int t = i >> 5, f = i & 31;
  float pos = (float)(t + seq_start[0]);
  float inv = powf(10000.0f, -(float)f * (1.0f / 32.0f));  // 10000^(-f/32)
  float a = pos * inv;
  sc[i] = make_float2(cosf(a), sinf(a));
}

// ---------------- MFMA GEMM: C[M][N] = A[M][K] * B[N][K]^T (bf16 in, m97 structure) ----------------
__device__ __forceinline__ void store_out(float* C, size_t i, float v) { C[i] = v; }
__device__ __forceinline__ void store_out(unsigned short* C, size_t i, float v) { C[i] = f2bfu(v); }

template <typename OutT>
__global__ __launch_bounds__(256) void gemm_bt(const unsigned short* __restrict__ A,
                                               const unsigned short* __restrict__ Bm,
                                               OutT* __restrict__ C, int M, int N, int K) {
  __shared__ __align__(16) unsigned short As[128 * 32];
  __shared__ __align__(16) unsigned short Bs[128 * 32];
  const int tid = threadIdx.x, lane = tid & 63, wv = tid >> 6;
  const int wm = wv >> 1, wn = wv & 1;
  const int row0 = blockIdx.y << 7, col0 = blockIdx.x << 7;
  const int lo = lane & 15, krd = (lane >> 4) << 3;
  f32x4 acc[4][4] = {};
  for (int kk = 0; kk < K; kk += 32) {
    __syncthreads();
#pragma unroll
    for (int half = 0; half < 2; ++half) {
      const int seg  = wv + (half << 2);             // wave-uniform LDS segment 0..7
      const int boff = seg * 1024 + lane * 16;       // byte offset in the 8 KB tile
      const int r    = boff >> 6;                    // row (64B per row of 32 bf16)
      const int ce   = (boff & 63) >> 1;             // element col
      GLOAD_LDS16(A  + (size_t)(row0 + r) * K + kk + ce, (char*)As + seg * 1024);
      GLOAD_LDS16(Bm + (size_t)(col0 + r) * K + kk + ce, (char*)Bs + seg * 1024);
    }
    asm volatile("s_waitcnt vmcnt(0)" ::: "memory");
    __syncthreads();
    short8 af[4], bf[4];
#pragma unroll
    for (int i = 0; i < 4; ++i)
      af[i] = *(const short8*)&As[((wm << 6) + (i << 4) + lo) * 32 + krd];
#pragma unroll
    for (int j = 0; j < 4; ++j)
      bf[j] = *(const short8*)&Bs[((wn << 6) + (j << 4) + lo) * 32 + krd];
#pragma unroll
    for (int i = 0; i < 4; ++i)
#pragma unroll
      for (int j = 0; j < 4; ++j)
        acc[i][j] = __builtin_amdgcn_mfma_f32_16x16x32_bf16(af[i], bf[j], acc[i][j], 0, 0, 0);
  }
#pragma unroll
  for (int i = 0; i < 4; ++i)
#pragma unroll
    for (int j = 0; j < 4; ++j) {
      const int r = row0 + (wm << 6) + (i << 4) + ((lane >> 4) << 2);
      const int c = col0 + (wn << 6) + (j << 4) + lo;
#pragma unroll
      for (int rr = 0; rr < 4; ++rr)
        store_out(C, (size_t)(r + rr) * N + c, acc[i][j][rr]);
    }
}

// ---------------- pass 2: in-place RMSNorm + RoPE on q/k inside qkv ----------------
__global__ __launch_bounds__(256) void norm_rope_kernel(const float2* __restrict__ sc,
                                                        unsigned short* __restrict__ qkv) {
  __shared__ float buf[4][128];
  const int wv = threadIdx.x >> 6, lane = threadIdx.x & 63;
  const int gid = blockIdx.x * 4 + wv;           // (tok, head) pair
  const int tok = gid / 20, hd = gid % 20;
  const int t = tok & (TSEQ - 1);
  unsigned short* row = qkv + (size_t)tok * QKVN + (hd < 16 ? hd * DH_ : 2048 + (hd - 16) * DH_);
  const unsigned int pp = *(const unsigned int*)(row + 2 * lane);
  float v0 = bfu2f((unsigned short)(pp & 0xffffu));
  float v1 = bfu2f((unsigned short)(pp >> 16));
  float ss = v0 * v0 + v1 * v1;
#pragma unroll
  for (int m = 1; m < 64; m <<= 1) ss += __shfl_xor(ss, m, 64);
  const float rn = rsqrtf(ss * (1.0f / 128.0f) + 1e-6f);
  v0 *= rn; v1 *= rn;
  if (lane < 32) {                               // rotary pair (x1,x2) = dims (2*lane, 2*lane+1)
    const float2 cs = sc[t * 32 + lane];
    buf[wv][lane]      = v0 * cs.x - v1 * cs.y;  // out dim lane
    buf[wv][lane + 32] = v0 * cs.y + v1 * cs.x;  // out dim lane+32
  } else {                                       // passthrough dims 64..127 (normalized)
    buf[wv][2 * lane]     = v0;
    buf[wv][2 * lane + 1] = v1;
  }
  const float o0 = buf[wv][2 * lane], o1 = buf[wv][2 * lane + 1];
  const unsigned int out = (unsigned int)f2bfu(o0) | ((unsigned int)f2bfu(o1) << 16);
  *(unsigned int*)(row + 2 * lane) = out;
}

// ---------------- pass 2b: V transpose  qkv v-section -> Vt[b][kv][d][T] ----------------
// grid (TSEQ/64, NB*NKV*2); 64x64 LDS tile transpose
__global__ __launch_bounds__(256) void vt_kernel(const unsigned short* __restrict__ qkv,
                                                 unsigned short* __restrict__ Vt) {
  __shared__ unsigned short tile[64][68];
  const int t0 = blockIdx.x << 6;
  const int bkv = blockIdx.y >> 1, dh = blockIdx.y & 1;   // bkv = b*4+kv, dh = d-half
  const int b = bkv >> 2, kv = bkv & 3;
  const int tx = threadIdx.x & 15, ty = threadIdx.x >> 4;
#pragma unroll
  for (int rr = 0; rr < 4; ++rr) {
    const int row = (rr << 4) + ty;              // t offset in tile
    const ushort4 v = *(const ushort4*)(qkv + (size_t)(b * TSEQ + t0 + row) * QKVN + 2560 +
                                        kv * DH_ + (dh << 6) + (tx << 2));
    *(ushort4*)&tile[row][tx << 2] = v;
  }
  __syncthreads();
#pragma unroll
  for (int rr = 0; rr < 4; ++rr) {
    const int drow = (rr << 4) + ty;             // d offset in half
    ushort4 o;
    o.x = tile[(tx << 2) + 0][drow];
    o.y = tile[(tx << 2) + 1][drow];
    o.z = tile[(tx << 2) + 2][drow];
    o.w = tile[(tx << 2) + 3][drow];
    *(ushort4*)(Vt + ((size_t)(bkv * DH_ + (dh << 6) + drow)) * TSEQ + t0 + (tx << 2)) = o;
  }
}

// ---------------- pass 3: MFMA causal flash attention (paired q-tiles, pre-transposed V) ----------------
// grid (16, NB*NHEAD); block px handles q-tiles {px, 31-px} -> uniform 66 K-tiles/block
__global__ __launch_bounds__(256) void attn_kernel(const unsigned short* __restrict__ qkv,
                                                   const unsigned short* __restrict__ Vt,
                                                   unsigned short* __restrict__ yb) {
  __shared__ __align__(16) unsigned short Ks[32][136];   // [key][d], padded
  __shared__ __align__(16) unsigned short Vs[128][40];   // [d][key], padded
  __shared__ __align__(16) unsigned short Ps[4][16][40]; // per-wave P bounce
  const int px = blockIdx.x, bh = blockIdx.y;
  const int b = bh >> 4, h = bh & 15, kv = h >> 2;       // h = kv*GROUPS + g
  const int tid = threadIdx.x, lane = tid & 63, wv = tid >> 6;
  const int lo = lane & 15, hi = lane >> 4;
  const unsigned short* base = qkv + (size_t)b * TSEQ * QKVN;
  const unsigned short* Vg = Vt + (size_t)(b * NKV + kv) * DH_ * TSEQ;

#pragma unroll
  for (int half = 0; half < 2; ++half) {
    const int qt = half ? (31 - px) : px;
    const int q0 = qt << 6;
    short8 qf[4];
#pragma unroll
    for (int ch = 0; ch < 4; ++ch)
      qf[ch] = *(const short8*)(base + (size_t)(q0 + (wv << 4) + lo) * QKVN + h * DH_ +
                                ch * 32 + hi * 8);
    float m_r[4] = {-1e30f, -1e30f, -1e30f, -1e30f};
    float l_r[4] = {0.f, 0.f, 0.f, 0.f};
    f32x4 oacc[8] = {};
    const int rbase = q0 + (wv << 4) + (hi << 2);
    for (int t0 = 0; t0 <= q0 + 63; t0 += 32) {
      __syncthreads();
#pragma unroll
      for (int it = 0; it < 2; ++it) {                 // stage K tile 32x128 (row stride QKVN)
        int idx = tid + (it << 8);
        int r = idx >> 4, c8 = (idx & 15) << 3;
        *(short8*)&Ks[r][c8] =
            *(const short8*)(base + (size_t)(t0 + r) * QKVN + 2048 + kv * DH_ + c8);
      }
#pragma unroll
      for (int it = 0; it < 2; ++it) {                 // stage V tile from Vt (vectorized)
        int idx = tid + (it << 8);
        int d = idx >> 2, c8 = (idx & 3) << 3;
        *(short8*)&Vs[d][c8] = *(const short8*)(Vg + (size_t)d * TSEQ + t0 + c8);
      }
      __syncthreads();
      f32x4 sacc[2] = {};
#pragma unroll
      for (int c = 0; c < 2; ++c)
#pragma unroll
        for (int ch = 0; ch < 4; ++ch) {
          short8 kf = *(const short8*)&Ks[(c << 4) + lo][ch * 32 + hi * 8];
          sacc[c] = __builtin_amdgcn_mfma_f32_16x16x32_bf16(qf[ch], kf, sacc[c], 0, 0, 0);
        }
      float p0[4], p1[4], tm[4];
#pragma unroll
      for (int r = 0; r < 4; ++r) {
        float s0 = sacc[0][r] * 0.12f, s1 = sacc[1][r] * 0.12f;
        const int rg = rbase + r;
        if (t0 + lo > rg)      s0 = -1e30f;            // causal mask
        if (t0 + 16 + lo > rg) s1 = -1e30f;
        p0[r] = s0; p1[r] = s1;
        tm[r] = fmaxf(s0, s1);
      }
#pragma unroll
      for (int mm = 1; mm < 16; mm <<= 1)
#pragma unroll
        for (int r = 0; r < 4; ++r) tm[r] = fmaxf(tm[r], __shfl_xor(tm[r], mm, 64));
      float fac[4], rs[4];
#pragma unroll
      for (int r = 0; r < 4; ++r) {
        float mn = fmaxf(m_r[r], tm[r]);
        fac[r] = __expf(m_r[r] - mn);
        m_r[r] = mn;
        p0[r] = __expf(p0[r] - mn);
        p1[r] = __expf(p1[r] - mn);
        rs[r] = p0[r] + p1[r];
      }
#pragma unroll
      for (int mm = 1; mm < 16; mm <<= 1)
#pragma unroll
        for (int r = 0; r < 4; ++r) rs[r] += __shfl_xor(rs[r], mm, 64);
#pragma unroll
      for (int r = 0; r < 4; ++r) l_r[r] = l_r[r] * fac[r] + rs[r];
#pragma unroll
      for (int dt = 0; dt < 8; ++dt)
#pragma unroll
        for (int r = 0; r < 4; ++r) oacc[dt][r] *= fac[r];
#pragma unroll
      for (int r = 0; r < 4; ++r) {                    // P (D-layout) -> LDS
        Ps[wv][(hi << 2) + r][lo]      = f2bfu(p0[r]);
        Ps[wv][(hi << 2) + r][16 + lo] = f2bfu(p1[r]);
      }
      short8 pf = *(const short8*)&Ps[wv][lo][hi * 8]; // P back in A-frag layout
#pragma unroll
      for (int dt = 0; dt < 8; ++dt) {
        short8 vf = *(const short8*)&Vs[(dt << 4) + lo][hi * 8];
        oacc[dt] = __builtin_amdgcn_mfma_f32_16x16x32_bf16(pf, vf, oacc[dt], 0, 0, 0);
      }
    }
#pragma unroll
    for (int r = 0; r < 4; ++r) {
      const int rg = rbase + r;
      const float inv = 1.0f / l_r[r];
#pragma unroll
      for (int dt = 0; dt < 8; ++dt)
        yb[(size_t)(b * TSEQ + rg) * (NHEAD * DH_) + h * DH_ + (dt << 4) + lo] =
            f2bfu(oacc[dt][r] * inv);
    }
  }
}

// ---------------- launcher ----------------
extern "C" void kernel_launch(void* const* d_in, const int* in_sizes, int n_in,
                              void* d_out, int out_size, void* d_ws, size_t ws_size,
                              hipStream_t stream) {
  const float* x   = (const float*)d_in[0];
  const int* seq0  = (const int*)d_in[1];
  // d_in[2] = attn_mask (tril causal) — handled analytically
  const float* wq  = (const float*)d_in[3];
  const float* wk  = (const float*)d_in[4];
  const float* wvp = (const float*)d_in[5];
  const float* wo  = (const float*)d_in[6];
  float* out = (float*)d_out;
  char* ws = (char*)d_ws;

  const size_t xb_e   = (size_t)NTOK * DIM_;              // 16,777,216
  const size_t wqkv_e = (size_t)QKVN * DIM_;              //  6,291,456
  const size_t wo_e   = (size_t)DIM_ * DIM_;              //  4,194,304
  const size_t qkv_e  = (size_t)NTOK * QKVN;              // 25,165,824

  unsigned short* xb    = (unsigned short*)ws;
  unsigned short* wqkvb = xb + xb_e;
  unsigned short* wob   = wqkvb + wqkv_e;
  unsigned short* qkvb  = wob + wo_e;
  float2* sc            = (float2*)(qkvb + qkv_e);
  unsigned short* yb    = xb;                             // xb dead after GEMM1 — reuse
  unsigned short* Vtb   = wqkvb;                          // wqkvb dead after GEMM1 — reuse (8.4MB <= 12.6MB)
  const size_t need = (size_t)((char*)(sc + TSEQ * 32) - ws);   // 105,381,888 B (known to fit)
  if (ws_size < need) {
    hipMemsetAsync(d_out, 0x7f, 256, stream);  // sentinel: absmax ~3.4e38 => ws too small
    return;
  }

  cvt_kernel<<<2048, 256, 0, stream>>>(x, xb, (int)(xb_e / 4));
  cvt_kernel<<<1024, 256, 0, stream>>>(wq, wqkvb, (int)(wo_e / 4));
  cvt_kernel<<<512, 256, 0, stream>>>(wk, wqkvb + (size_t)2048 * DIM_, (int)((size_t)512 * DIM_ / 4));
  cvt_kernel<<<512, 256, 0, stream>>>(wvp, wqkvb + (size_t)2560 * DIM_, (int)((size_t)512 * DIM_ / 4));
  cvt_kernel<<<1024, 256, 0, stream>>>(wo, wob, (int)(wo_e / 4));
  rope_table_kernel<<<(TSEQ * 32) / 256, 256, 0, stream>>>(seq0, sc);

  // qkv = x @ [wq;wk;wv]^T  -> natural layout [tok][3072] (bf16)
  gemm_bt<unsigned short><<<dim3(QKVN / 128, NTOK / 128), 256, 0, stream>>>(
      xb, wqkvb, qkvb, NTOK, QKVN, DIM_);

  // in-place rmsnorm + rope on q,k heads; V transpose into Vt (reuses wqkvb space)
  norm_rope_kernel<<<NTOK * 20 / 4, 256, 0, stream>>>(sc, qkvb);
  vt_kernel<<<dim3(TSEQ / 64, NB * NKV * 2), 256, 0, stream>>>(qkvb, Vtb);

  // MFMA causal flash attention (balanced pairing)
  attn_kernel<<<dim3(16, NB * NHEAD), 256, 0, stream>>>(qkvb, Vtb, yb);

  // out = y @ wo^T   (bf16 in, fp32 out)
  gemm_bt<float><<<dim3(DIM_ / 128, NTOK / 128), 256, 0, stream>>>(
      yb, wob, out, NTOK, DIM_, DIM_);
}